// Round 1
// baseline (269.494 us; speedup 1.0000x reference)
//
#include <hip/hip_runtime.h>
#include <hip/hip_bf16.h>

#define FEATURES 1024
#define NROWS (8 * 2048)

// One block per output row. 256 threads x float4 = 1024 floats = one row.
__global__ __launch_bounds__(256) void embed_gather(
    const int* __restrict__ idxes,
    const float* __restrict__ weight,
    float* __restrict__ out)
{
    int row = blockIdx.x;            // 0 .. NROWS-1
    int t = threadIdx.x;             // 0 .. 255
    int src = idxes[row];            // weight row index

    const float4* __restrict__ wrow =
        (const float4*)(weight + (size_t)src * FEATURES);
    float4* __restrict__ orow =
        (float4*)(out + (size_t)row * FEATURES);

    orow[t] = wrow[t];
}

extern "C" void kernel_launch(void* const* d_in, const int* in_sizes, int n_in,
                              void* d_out, int out_size, void* d_ws, size_t ws_size,
                              hipStream_t stream) {
    const int* idxes = (const int*)d_in[0];       // [8,2048] int32
    const float* weight = (const float*)d_in[1];  // [50257,1024] fp32
    float* out = (float*)d_out;                   // [8,2048,1024] fp32

    embed_gather<<<NROWS, 256, 0, stream>>>(idxes, weight, out);
}